// Round 9
// baseline (284.369 us; speedup 1.0000x reference)
//
#include <hip/hip_runtime.h>
#include <math.h>

// ---------------------------------------------------------------------------
// GatedDirGCNConv — r19: r18 base (best 274.3 µs) + edge_w MLP restructure.
//   Diagnosis: edge_w (80 µs, rank-1 five rounds running) is NOT at an
//   atomic-throughput wall (1.6M ops / 80µs = 8.3 ops/cy chip-wide, far
//   under TCC capability with 100K independent addresses). It is
//   LATENCY-bound: 8 edges/wave, atomics issued from 8 lanes, wave parks
//   ~600cy on the returned slot before the dependent rec store.
//   Fix: 32 edges/wave. 4 batches of the EXACT old 8-lane LCS math
//   (bit-identical per-edge fp order), then redistribute z via shuffles so
//   lane l = edge (l>>1), side (l&1): ONE 64-lane atomic instruction
//   (32 edges x 2 sides) + one predicated store. Per-wave atomic MLP 16->64,
//   wave count 100K->25K, Wl2 loads amortized 4x.
//   K1 proj_zero : r14/r18 (2-col register blocking).
//   K3 gather_gate: r18 (split loops, rsqrt, 4-node batched gate MLP).
// ---------------------------------------------------------------------------

typedef unsigned long long u64;

#define SLOTS 56   // max row len; P(Poisson(16) >= 56) ~ 5e-15 per side

__device__ __forceinline__ float bflo(unsigned u) { return __uint_as_float(u << 16); }
__device__ __forceinline__ float bfhi(unsigned u) { return __uint_as_float(u & 0xffff0000u); }
__device__ __forceinline__ unsigned rne16(float f) {   // fp32 -> bf16 bits, RNE
    unsigned u = __float_as_uint(f);
    return (u + 0x7fffu + ((u >> 16) & 1u)) >> 16;
}

// K1: fused node projection + zero pk + swizzle Wg1.  (r14/r18)
__global__ __launch_bounds__(256) void proj_zero_kernel(
    const float* __restrict__ x,
    const float* __restrict__ Wl1,  const float* __restrict__ bl1,
    const float* __restrict__ Ws2d, const float* __restrict__ bs2d,
    const float* __restrict__ Wd2s, const float* __restrict__ bd2s,
    const float* __restrict__ Wg1,  float* __restrict__ Wg1q,
    float* __restrict__ A, float* __restrict__ B,
    unsigned* __restrict__ Ah, unsigned* __restrict__ Bh,
    unsigned* __restrict__ HSh, unsigned* __restrict__ HDh,
    int4* __restrict__ zp4, int nz4, int PB, int N)
{
    if (blockIdx.x >= PB) {
        if (blockIdx.x == PB + 64) {               // Wg1 swizzle
            for (int i = threadIdx.x; i < 8192; i += 256) {
                const int k = i >> 6, c = i & 63;
                Wg1q[((k >> 2) * 64 + c) * 4 + (k & 3)] = Wg1[i];
            }
            return;
        }
        const int t0 = (blockIdx.x - PB) * 256 + threadIdx.x;   // zero pk
        const int stride = 64 * 256;
        const int4 z = make_int4(0, 0, 0, 0);
        for (int i = t0; i < nz4; i += stride) zp4[i] = z;
        return;
    }
    __shared__ float xs[64][64];
    const int tid  = threadIdx.x;
    const int n0   = blockIdx.x * 64;
    const int wv   = tid >> 6;
    const int cc   = tid & 63;
    const int side = wv & 1;      // 0: {Wl1a->A/Ah, Ws2d->HSh}; 1: {Wl1b->B/Bh, Wd2s->HDh}
    const int par  = wv >> 1;     // node parity within tile

    const float* W0 = side ? (Wl1 + 64 * 64) : Wl1;
    const float* W1 = side ? Wd2s : Ws2d;
    const float  b0 = side ? 0.f : bl1[cc];
    const float  b1 = side ? bd2s[cc] : bs2d[cc];
    float*    oA  = side ? B  : A;
    unsigned* oAh = side ? Bh : Ah;
    unsigned* oH  = side ? HDh : HSh;

    float w0[64], w1[64];
#pragma unroll
    for (int k = 0; k < 64; ++k) {
        w0[k] = W0[k * 64 + cc];
        w1[k] = W1[k * 64 + cc];
    }

#pragma unroll
    for (int j = 0; j < 4; ++j) {
        int f4  = tid + j * 256;
        int row = f4 >> 4;
        int c4  = f4 & 15;
        int gn  = n0 + row;
        float4 v = (gn < N) ? ((const float4*)x)[(long)gn * 16 + c4]
                            : make_float4(0.f, 0.f, 0.f, 0.f);
        ((float4*)&xs[row][0])[c4] = v;
    }
    __syncthreads();

    const int nmax = (N - n0 < 64) ? (N - n0) : 64;
    for (int n = par; n < nmax; n += 2) {
        float a0 = b0, a1 = b1;
#pragma unroll
        for (int k = 0; k < 64; k += 4) {
            float4 xv = *((const float4*)&xs[n][k]);
            a0 += xv.x * w0[k] + xv.y * w0[k + 1] + xv.z * w0[k + 2] + xv.w * w0[k + 3];
            a1 += xv.x * w1[k] + xv.y * w1[k + 1] + xv.z * w1[k + 2] + xv.w * w1[k + 3];
        }
        const long gn = n0 + n;
        oA[gn * 64 + cc] = a0;
        const float p0 = __shfl_xor(a0, 1);        // partner feature cc^1
        const float p1 = __shfl_xor(a1, 1);
        if ((cc & 1) == 0) {                       // even lane packs (cc, cc+1)
            oAh[gn * 32 + (cc >> 1)] = (rne16(p0) << 16) | rne16(a0);
            oH [gn * 32 + (cc >> 1)] = (rne16(p1) << 16) | rne16(a1);
        }
    }
}

// K2: LCS keep + u64 atomics + direct padded-row record placement.
// 32 edges/wave: 4 batches of the old 8-lane LCS (bit-identical math),
// then ONE 64-lane atomic (lane l -> edge l>>1, side l&1).
#define LCS_MARGIN 0.04f
__global__ __launch_bounds__(256) void edge_w_kernel(
    const int* __restrict__ src, const int* __restrict__ dst,
    const float* __restrict__ counts,
    const float* __restrict__ A, const float* __restrict__ B,
    const unsigned* __restrict__ Ah, const unsigned* __restrict__ Bh,
    const float* __restrict__ Wl2, const float* __restrict__ bl2,
    u64* __restrict__ pk, unsigned* __restrict__ rec, int N, int E)
{
    const int tid  = threadIdx.x;
    const int lane = tid & 63;
    const int wv   = tid >> 6;
    const int base = blockIdx.x * 128 + wv * 32;   // first edge of this wave
    const int c    = lane & 7;                     // features 8c..8c+7

    const float4 wl0 = *((const float4*)(Wl2 + c * 8));
    const float4 wl1 = *((const float4*)(Wl2 + c * 8 + 4));
    const float  bl  = bl2[0];

    float zb[4];
#pragma unroll
    for (int b = 0; b < 4; ++b) {
        const int e  = base + b * 8 + (lane >> 3);
        const int ec = (e < E) ? e : 0;            // clamped: junk z unused
        const int s = src[ec];
        const int d = dst[ec];
        const uint4 ua = *((const uint4*)(Ah + (long)s * 32 + c * 4));
        const uint4 ub = *((const uint4*)(Bh + (long)d * 32 + c * 4));

        float p = fmaxf(bflo(ua.x) + bflo(ub.x), 0.f) * wl0.x
                + fmaxf(bfhi(ua.x) + bfhi(ub.x), 0.f) * wl0.y
                + fmaxf(bflo(ua.y) + bflo(ub.y), 0.f) * wl0.z
                + fmaxf(bfhi(ua.y) + bfhi(ub.y), 0.f) * wl0.w
                + fmaxf(bflo(ua.z) + bflo(ub.z), 0.f) * wl1.x
                + fmaxf(bfhi(ua.z) + bfhi(ub.z), 0.f) * wl1.y
                + fmaxf(bflo(ua.w) + bflo(ub.w), 0.f) * wl1.z
                + fmaxf(bfhi(ua.w) + bfhi(ub.w), 0.f) * wl1.w;
        p += __shfl_xor(p, 1); p += __shfl_xor(p, 2); p += __shfl_xor(p, 4);

        float z = p + bl;
        if (fabsf(z) < LCS_MARGIN) {    // borderline (~3%): exact fp32 recheck
            const float4 a0 = *((const float4*)(A + (long)s * 64 + c * 8));
            const float4 a1 = *((const float4*)(A + (long)s * 64 + c * 8 + 4));
            const float4 b0 = *((const float4*)(B + (long)d * 64 + c * 8));
            const float4 b1 = *((const float4*)(B + (long)d * 64 + c * 8 + 4));
            float q = fmaxf(a0.x + b0.x, 0.f) * wl0.x + fmaxf(a0.y + b0.y, 0.f) * wl0.y
                    + fmaxf(a0.z + b0.z, 0.f) * wl0.z + fmaxf(a0.w + b0.w, 0.f) * wl0.w
                    + fmaxf(a1.x + b1.x, 0.f) * wl1.x + fmaxf(a1.y + b1.y, 0.f) * wl1.y
                    + fmaxf(a1.z + b1.z, 0.f) * wl1.z + fmaxf(a1.w + b1.w, 0.f) * wl1.w;
            q += __shfl_xor(q, 1); q += __shfl_xor(q, 2); q += __shfl_xor(q, 4);
            z = q + bl;
        }
        zb[b] = z;
    }

    // redistribute: lane l handles edge m = l>>1 of this wave, side = l&1
    const int m = lane >> 1;
    const int srcl = (m & 7) * 8;                  // lane holding z (c==0)
    const float z0 = __shfl(zb[0], srcl);
    const float z1 = __shfl(zb[1], srcl);
    const float z2 = __shfl(zb[2], srcl);
    const float z3 = __shfl(zb[3], srcl);
    const int bsel = m >> 3;
    const float z = (bsel == 0) ? z0 : (bsel == 1) ? z1 : (bsel == 2) ? z2 : z3;

    const int e = base + m;
    if (e < E) {
        const int side = lane & 1;
        const int s = src[e];                      // L1-hot reload
        const int d = dst[e];
        const u64 keep = (z >= 0.f) ? 1ull : 0ull; // sigmoid(z)>=0.5 <=> z>=0
        const unsigned ic = (unsigned)__float2int_rn(counts[e]);  // {1..4}
        const long node = side ? (long)(N + s) : (long)d;
        const u64 old = atomicAdd(pk + node, (keep << 32) | (u64)ic);
        if (keep) {
            const unsigned other = side ? (unsigned)d : (unsigned)s;
            rec[node * SLOTS + (int)(old >> 32)] = (other << 16) | ic;
        }
    }
}

// K3: one wave per 4 nodes; SPLIT in/out gather loops, rsqrtf,
// batched gate MLP (4 nodes/Wg1q frag).  (r18)
__global__ __launch_bounds__(256) void gather_gate_kernel(
    const u64* __restrict__ pk, const unsigned* __restrict__ rec,
    const unsigned* __restrict__ HSh, const unsigned* __restrict__ HDh,
    const float* __restrict__ x,
    const float* __restrict__ Wg1q, const float* __restrict__ bg1,
    const float* __restrict__ Wg2, const float* __restrict__ bg2,
    float* __restrict__ out, int N)
{
    __shared__ float mbuf[16][128];
    const int tid  = threadIdx.x;
    const int wv   = tid >> 6;
    const int lane = tid & 63;
    const int g    = lane >> 3;        // edge group 0..7
    const int c    = lane & 7;         // feature slice: features 8c..8c+7
    const int nb   = blockIdx.x * 16 + wv * 4;     // first node of this wave

    const unsigned* pklo = (const unsigned*)pk;    // lo32 of pk[i] at index 2i

    for (int j = 0; j < 4; ++j) {
        const int n   = nb + j;
        const int row = wv * 4 + j;
        if (n >= N) {
            if (g == 0) {
#pragma unroll
                for (int q = 0; q < 8; ++q) {
                    mbuf[row][c * 8 + q]      = 0.f;
                    mbuf[row][64 + c * 8 + q] = 0.f;
                }
            }
            continue;
        }

        const u64 pin  = pk[n];
        const u64 pout = pk[N + n];
        const int ei = (int)(pin >> 32);
        const int eo = (int)(pout >> 32);
        const float qin  = rsqrtf(fmaxf((float)(unsigned)pin,  1.f)); // isq_in[n]
        const float qout = rsqrtf(fmaxf((float)(unsigned)pout, 1.f)); // isq_out[n]
        const unsigned* rin  = rec + (long)n * SLOTS;
        const unsigned* rout = rec + (long)(N + n) * SLOTS;

        float mi[8], mo[8];
#pragma unroll
        for (int q = 0; q < 8; ++q) { mi[q] = 0.f; mo[q] = 0.f; }

        // ---- inbound records (m_in side): w = cnt * rsqrt(deg_out[src])
        for (int ii = g; ii < ei; ii += 8) {
            const unsigned ra = rin[ii];
            const unsigned sa = ra >> 16;
            const float dga = (float)pklo[2 * (N + (int)sa)];   // deg_out[sa]
            const float wa  = (float)(ra & 0xFFu) * rsqrtf(fmaxf(dga, 1.f));
            const uint4 ua = *((const uint4*)(HSh + (long)sa * 32 + c * 4));
            mi[0] += wa * bflo(ua.x);  mi[1] += wa * bfhi(ua.x);
            mi[2] += wa * bflo(ua.y);  mi[3] += wa * bfhi(ua.y);
            mi[4] += wa * bflo(ua.z);  mi[5] += wa * bfhi(ua.z);
            mi[6] += wa * bflo(ua.w);  mi[7] += wa * bfhi(ua.w);
        }
        // ---- outbound records (m_out side): w = cnt * rsqrt(deg_in[dst])
        for (int jo = g; jo < eo; jo += 8) {
            const unsigned rb = rout[jo];
            const unsigned sb = rb >> 16;
            const float dgb = (float)pklo[2 * (int)sb];         // deg_in[sb]
            const float wb  = (float)(rb & 0xFFu) * rsqrtf(fmaxf(dgb, 1.f));
            const uint4 ub = *((const uint4*)(HDh + (long)sb * 32 + c * 4));
            mo[0] += wb * bflo(ub.x);  mo[1] += wb * bfhi(ub.x);
            mo[2] += wb * bflo(ub.y);  mo[3] += wb * bfhi(ub.y);
            mo[4] += wb * bflo(ub.z);  mo[5] += wb * bfhi(ub.z);
            mo[6] += wb * bflo(ub.w);  mo[7] += wb * bfhi(ub.w);
        }

        // reduce the 8 edge groups (lane bits 3,4,5)
#pragma unroll
        for (int q = 0; q < 8; ++q) {
            mi[q] += __shfl_xor(mi[q], 8);
            mi[q] += __shfl_xor(mi[q], 16);
            mi[q] += __shfl_xor(mi[q], 32);
            mo[q] += __shfl_xor(mo[q], 8);
            mo[q] += __shfl_xor(mo[q], 16);
            mo[q] += __shfl_xor(mo[q], 32);
        }
        if (g == 0) {
#pragma unroll
            for (int q = 0; q < 8; ++q) {
                mbuf[row][c * 8 + q]      = mi[q] * qin;    // apply row norm factor
                mbuf[row][64 + c * 8 + q] = mo[q] * qout;
            }
        }
    }
    // wave-local LDS RAW; compiler inserts lgkmcnt wait (no barrier needed)

    const float bgv = bg1[lane];
    float ac0 = bgv, ac1 = bgv, ac2 = bgv, ac3 = bgv;
    const float* m0 = &mbuf[wv * 4 + 0][0];
    const float* m1 = &mbuf[wv * 4 + 1][0];
    const float* m2 = &mbuf[wv * 4 + 2][0];
    const float* m3 = &mbuf[wv * 4 + 3][0];
#pragma unroll 4
    for (int k4 = 0; k4 < 32; ++k4) {
        const float4 w4 = ((const float4*)Wg1q)[k4 * 64 + lane];   // coalesced, L1
        const float4 q0 = ((const float4*)m0)[k4];                 // LDS broadcast
        const float4 q1 = ((const float4*)m1)[k4];
        const float4 q2 = ((const float4*)m2)[k4];
        const float4 q3 = ((const float4*)m3)[k4];
        ac0 += q0.x * w4.x + q0.y * w4.y + q0.z * w4.z + q0.w * w4.w;
        ac1 += q1.x * w4.x + q1.y * w4.y + q1.z * w4.z + q1.w * w4.w;
        ac2 += q2.x * w4.x + q2.y * w4.y + q2.z * w4.z + q2.w * w4.w;
        ac3 += q3.x * w4.x + q3.y * w4.y + q3.z * w4.z + q3.w * w4.w;
    }
    const float wg2 = Wg2[lane];
    float v0 = fmaxf(ac0, 0.f) * wg2;
    float v1 = fmaxf(ac1, 0.f) * wg2;
    float v2 = fmaxf(ac2, 0.f) * wg2;
    float v3 = fmaxf(ac3, 0.f) * wg2;
#pragma unroll
    for (int m = 1; m <= 32; m <<= 1) {
        v0 += __shfl_xor(v0, m);
        v1 += __shfl_xor(v1, m);
        v2 += __shfl_xor(v2, m);
        v3 += __shfl_xor(v3, m);
    }
    const float bb = bg2[0];
    float gt[4];
    gt[0] = 1.f / (1.f + expf(-(v0 + bb)));
    gt[1] = 1.f / (1.f + expf(-(v1 + bb)));
    gt[2] = 1.f / (1.f + expf(-(v2 + bb)));
    gt[3] = 1.f / (1.f + expf(-(v3 + bb)));

#pragma unroll
    for (int j = 0; j < 4; ++j) {
        const int n = nb + j;
        if (n >= N) continue;
        const float miv = mbuf[wv * 4 + j][lane];
        const float mov = mbuf[wv * 4 + j][64 + lane];
        out[(long)n * 64 + lane] = 0.5f * gt[j] * miv + 0.5f * (1.f - gt[j]) * mov
                                 + x[(long)n * 64 + lane];
    }
}

extern "C" void kernel_launch(void* const* d_in, const int* in_sizes, int n_in,
                              void* d_out, int out_size, void* d_ws, size_t ws_size,
                              hipStream_t stream) {
    const float* x      = (const float*)d_in[0];
    const float* counts = (const float*)d_in[1];
    const float* Ws2d   = (const float*)d_in[2];
    const float* bs2d   = (const float*)d_in[3];
    const float* Wd2s   = (const float*)d_in[4];
    const float* bd2s   = (const float*)d_in[5];
    const float* Wl1    = (const float*)d_in[6];
    const float* bl1    = (const float*)d_in[7];
    const float* Wl2    = (const float*)d_in[8];
    const float* bl2    = (const float*)d_in[9];
    const float* Wg1    = (const float*)d_in[10];
    const float* bg1    = (const float*)d_in[11];
    const float* Wg2    = (const float*)d_in[12];
    const float* bg2    = (const float*)d_in[13];
    const int*   src    = (const int*)d_in[14];
    const int*   dst    = (const int*)d_in[15];

    const int N  = in_sizes[0] / 64;
    const int E  = in_sizes[14];
    const int PB = (N + 63) / 64;              // proj blocks

    float* ws      = (float*)d_ws;
    float* Wg1q    = ws;                       // 8192 floats
    float* A       = ws + 8192;                // 64N fp32
    float* B       = A + 64L * N;              // 64N fp32
    unsigned* Ah   = (unsigned*)(B + 64L * N); // 32N packed bf16
    unsigned* Bh   = Ah + 32L * N;
    unsigned* HSh  = Bh + 32L * N;
    unsigned* HDh  = HSh + 32L * N;
    u64* pk        = (u64*)(HDh + 32L * N);    // 2N u64 (even offset -> 8B ok)
    unsigned* rec  = (unsigned*)(pk + 2L * N); // 2N * SLOTS u32 (padded rows)

    proj_zero_kernel<<<PB + 65, 256, 0, stream>>>(
        x, Wl1, bl1, Ws2d, bs2d, Wd2s, bd2s, Wg1, Wg1q,
        A, B, Ah, Bh, HSh, HDh, (int4*)pk, N, PB, N);   // 2N u64 = N int4

    edge_w_kernel<<<(E + 127) / 128, 256, 0, stream>>>(
        src, dst, counts, A, B, Ah, Bh, Wl2, bl2, pk, rec, N, E);

    gather_gate_kernel<<<(N + 15) / 16, 256, 0, stream>>>(
        pk, rec, HSh, HDh, x, Wg1q, bg1, Wg2, bg2, (float*)d_out, N);
}

// Round 10
// 274.625 us; speedup vs baseline: 1.0355x; 1.0355x over previous
//
#include <hip/hip_runtime.h>
#include <math.h>

// ---------------------------------------------------------------------------
// GatedDirGCNConv — r20: r18 base (best 274.3 µs). r19's 64-lane-atomic K2
// REVERTED (91.5 µs vs 80, VALUBusy 22->15, +200K LDS conflicts: less TLP,
// per-lane TCC processing anyway). Atomic wall confirmed 3 ways (r13 pad,
// r19 restructure, 5 rounds at ~80) -> K2 frozen at r18.
// New in r20 (K3 critical path):
//   (a) isq_kernel: precompute isq[2N] = rsqrtf(max(deg,1)) after K2 (~3 µs)
//       -> K3's per-record chain rec->deg(u32)->cvt->fmax->rsqrt becomes
//       rec->isq(float load); removes redundant 8-lane VALU chain.
//   (b) 2-way unroll of K3 record loops (ii, ii+8 per iter; accumulation
//       order preserved -> bit-identical FP) doubles outstanding loads.
//   K1 proj_zero : r14/r18 (2-col register blocking).
// ---------------------------------------------------------------------------

typedef unsigned long long u64;

#define SLOTS 56   // max row len; P(Poisson(16) >= 56) ~ 5e-15 per side

__device__ __forceinline__ float bflo(unsigned u) { return __uint_as_float(u << 16); }
__device__ __forceinline__ float bfhi(unsigned u) { return __uint_as_float(u & 0xffff0000u); }
__device__ __forceinline__ unsigned rne16(float f) {   // fp32 -> bf16 bits, RNE
    unsigned u = __float_as_uint(f);
    return (u + 0x7fffu + ((u >> 16) & 1u)) >> 16;
}

// K1: fused node projection + zero pk + swizzle Wg1.  (r14/r18)
__global__ __launch_bounds__(256) void proj_zero_kernel(
    const float* __restrict__ x,
    const float* __restrict__ Wl1,  const float* __restrict__ bl1,
    const float* __restrict__ Ws2d, const float* __restrict__ bs2d,
    const float* __restrict__ Wd2s, const float* __restrict__ bd2s,
    const float* __restrict__ Wg1,  float* __restrict__ Wg1q,
    float* __restrict__ A, float* __restrict__ B,
    unsigned* __restrict__ Ah, unsigned* __restrict__ Bh,
    unsigned* __restrict__ HSh, unsigned* __restrict__ HDh,
    int4* __restrict__ zp4, int nz4, int PB, int N)
{
    if (blockIdx.x >= PB) {
        if (blockIdx.x == PB + 64) {               // Wg1 swizzle
            for (int i = threadIdx.x; i < 8192; i += 256) {
                const int k = i >> 6, c = i & 63;
                Wg1q[((k >> 2) * 64 + c) * 4 + (k & 3)] = Wg1[i];
            }
            return;
        }
        const int t0 = (blockIdx.x - PB) * 256 + threadIdx.x;   // zero pk
        const int stride = 64 * 256;
        const int4 z = make_int4(0, 0, 0, 0);
        for (int i = t0; i < nz4; i += stride) zp4[i] = z;
        return;
    }
    __shared__ float xs[64][64];
    const int tid  = threadIdx.x;
    const int n0   = blockIdx.x * 64;
    const int wv   = tid >> 6;
    const int cc   = tid & 63;
    const int side = wv & 1;      // 0: {Wl1a->A/Ah, Ws2d->HSh}; 1: {Wl1b->B/Bh, Wd2s->HDh}
    const int par  = wv >> 1;     // node parity within tile

    const float* W0 = side ? (Wl1 + 64 * 64) : Wl1;
    const float* W1 = side ? Wd2s : Ws2d;
    const float  b0 = side ? 0.f : bl1[cc];
    const float  b1 = side ? bd2s[cc] : bs2d[cc];
    float*    oA  = side ? B  : A;
    unsigned* oAh = side ? Bh : Ah;
    unsigned* oH  = side ? HDh : HSh;

    float w0[64], w1[64];
#pragma unroll
    for (int k = 0; k < 64; ++k) {
        w0[k] = W0[k * 64 + cc];
        w1[k] = W1[k * 64 + cc];
    }

#pragma unroll
    for (int j = 0; j < 4; ++j) {
        int f4  = tid + j * 256;
        int row = f4 >> 4;
        int c4  = f4 & 15;
        int gn  = n0 + row;
        float4 v = (gn < N) ? ((const float4*)x)[(long)gn * 16 + c4]
                            : make_float4(0.f, 0.f, 0.f, 0.f);
        ((float4*)&xs[row][0])[c4] = v;
    }
    __syncthreads();

    const int nmax = (N - n0 < 64) ? (N - n0) : 64;
    for (int n = par; n < nmax; n += 2) {
        float a0 = b0, a1 = b1;
#pragma unroll
        for (int k = 0; k < 64; k += 4) {
            float4 xv = *((const float4*)&xs[n][k]);
            a0 += xv.x * w0[k] + xv.y * w0[k + 1] + xv.z * w0[k + 2] + xv.w * w0[k + 3];
            a1 += xv.x * w1[k] + xv.y * w1[k + 1] + xv.z * w1[k + 2] + xv.w * w1[k + 3];
        }
        const long gn = n0 + n;
        oA[gn * 64 + cc] = a0;
        const float p0 = __shfl_xor(a0, 1);        // partner feature cc^1
        const float p1 = __shfl_xor(a1, 1);
        if ((cc & 1) == 0) {                       // even lane packs (cc, cc+1)
            oAh[gn * 32 + (cc >> 1)] = (rne16(p0) << 16) | rne16(a0);
            oH [gn * 32 + (cc >> 1)] = (rne16(p1) << 16) | rne16(a1);
        }
    }
}

// K2: LCS keep + u64 atomics + direct padded-row record placement. (r18)
// pk[0..N) = dst side, pk[N..2N) = src side.  Frozen at the atomic floor.
#define LCS_MARGIN 0.04f
__global__ __launch_bounds__(256) void edge_w_kernel(
    const int* __restrict__ src, const int* __restrict__ dst,
    const float* __restrict__ counts,
    const float* __restrict__ A, const float* __restrict__ B,
    const unsigned* __restrict__ Ah, const unsigned* __restrict__ Bh,
    const float* __restrict__ Wl2, const float* __restrict__ bl2,
    u64* __restrict__ pk, unsigned* __restrict__ rec, int N, int E)
{
    const int tid = threadIdx.x;
    const int e   = blockIdx.x * 32 + (tid >> 3);
    const int c   = tid & 7;                     // features 8c..8c+7
    if (e >= E) return;

    const int s = src[e];
    const int d = dst[e];
    const uint4  ua  = *((const uint4*)(Ah + (long)s * 32 + c * 4));
    const uint4  ub  = *((const uint4*)(Bh + (long)d * 32 + c * 4));
    const float4 wl0 = *((const float4*)(Wl2 + c * 8));
    const float4 wl1 = *((const float4*)(Wl2 + c * 8 + 4));

    float p = fmaxf(bflo(ua.x) + bflo(ub.x), 0.f) * wl0.x
            + fmaxf(bfhi(ua.x) + bfhi(ub.x), 0.f) * wl0.y
            + fmaxf(bflo(ua.y) + bflo(ub.y), 0.f) * wl0.z
            + fmaxf(bfhi(ua.y) + bfhi(ub.y), 0.f) * wl0.w
            + fmaxf(bflo(ua.z) + bflo(ub.z), 0.f) * wl1.x
            + fmaxf(bfhi(ua.z) + bfhi(ub.z), 0.f) * wl1.y
            + fmaxf(bflo(ua.w) + bflo(ub.w), 0.f) * wl1.z
            + fmaxf(bfhi(ua.w) + bfhi(ub.w), 0.f) * wl1.w;
    p += __shfl_xor(p, 1); p += __shfl_xor(p, 2); p += __shfl_xor(p, 4);

    float z = p + bl2[0];
    if (fabsf(z) < LCS_MARGIN) {        // borderline (~3%): exact fp32 recheck
        const float4 a0 = *((const float4*)(A + (long)s * 64 + c * 8));
        const float4 a1 = *((const float4*)(A + (long)s * 64 + c * 8 + 4));
        const float4 b0 = *((const float4*)(B + (long)d * 64 + c * 8));
        const float4 b1 = *((const float4*)(B + (long)d * 64 + c * 8 + 4));
        float q = fmaxf(a0.x + b0.x, 0.f) * wl0.x + fmaxf(a0.y + b0.y, 0.f) * wl0.y
                + fmaxf(a0.z + b0.z, 0.f) * wl0.z + fmaxf(a0.w + b0.w, 0.f) * wl0.w
                + fmaxf(a1.x + b1.x, 0.f) * wl1.x + fmaxf(a1.y + b1.y, 0.f) * wl1.y
                + fmaxf(a1.z + b1.z, 0.f) * wl1.z + fmaxf(a1.w + b1.w, 0.f) * wl1.w;
        q += __shfl_xor(q, 1); q += __shfl_xor(q, 2); q += __shfl_xor(q, 4);
        z = q + bl2[0];
    }

    if (c == 0) {
        const u64 keep = (z >= 0.f) ? 1ull : 0ull;   // sigmoid(z)>=0.5 <=> z>=0
        const unsigned ic = (unsigned)__float2int_rn(counts[e]);  // {1..4} exact
        const u64 od = atomicAdd(pk + d,     (keep << 32) | (u64)ic);
        const u64 os = atomicAdd(pk + N + s, (keep << 32) | (u64)ic);
        if (keep) {
            rec[(long)d * SLOTS + (int)(od >> 32)]       = ((unsigned)s << 16) | ic;
            rec[(long)(N + s) * SLOTS + (int)(os >> 32)] = ((unsigned)d << 16) | ic;
        }
    }
}

// K2.5: isq[i] = rsqrt(max(deg_i,1)) for both sides (2N). ~3 µs.
__global__ __launch_bounds__(256) void isq_kernel(
    const u64* __restrict__ pk, float* __restrict__ isq, int M)
{
    const int i = blockIdx.x * 256 + threadIdx.x;
    if (i < M) isq[i] = rsqrtf(fmaxf((float)(unsigned)pk[i], 1.f));
}

// K3: one wave per 4 nodes; split in/out loops with 2-way unroll (double
// MLP), isq-table weights (no per-record rsqrt chain); batched gate MLP.
__global__ __launch_bounds__(256) void gather_gate_kernel(
    const u64* __restrict__ pk, const unsigned* __restrict__ rec,
    const float* __restrict__ isq,
    const unsigned* __restrict__ HSh, const unsigned* __restrict__ HDh,
    const float* __restrict__ x,
    const float* __restrict__ Wg1q, const float* __restrict__ bg1,
    const float* __restrict__ Wg2, const float* __restrict__ bg2,
    float* __restrict__ out, int N)
{
    __shared__ float mbuf[16][128];
    const int tid  = threadIdx.x;
    const int wv   = tid >> 6;
    const int lane = tid & 63;
    const int g    = lane >> 3;        // edge group 0..7
    const int c    = lane & 7;         // feature slice: features 8c..8c+7
    const int nb   = blockIdx.x * 16 + wv * 4;     // first node of this wave

    for (int j = 0; j < 4; ++j) {
        const int n   = nb + j;
        const int row = wv * 4 + j;
        if (n >= N) {
            if (g == 0) {
#pragma unroll
                for (int q = 0; q < 8; ++q) {
                    mbuf[row][c * 8 + q]      = 0.f;
                    mbuf[row][64 + c * 8 + q] = 0.f;
                }
            }
            continue;
        }

        const int ei = (int)(pk[n] >> 32);
        const int eo = (int)(pk[N + n] >> 32);
        const float qin  = isq[n];
        const float qout = isq[N + n];
        const unsigned* rin  = rec + (long)n * SLOTS;
        const unsigned* rout = rec + (long)(N + n) * SLOTS;

        float mi[8], mo[8];
#pragma unroll
        for (int q = 0; q < 8; ++q) { mi[q] = 0.f; mo[q] = 0.f; }

        // ---- inbound records (m_in side): w = cnt * isq_out[src]
        int ii = g;
        for (; ii + 8 < ei; ii += 16) {            // 2-way: ii, ii+8
            const unsigned r1 = rin[ii];
            const unsigned r2 = rin[ii + 8];
            const unsigned s1 = r1 >> 16;
            const unsigned s2 = r2 >> 16;
            const float w1 = (float)(r1 & 0xFFu) * isq[N + (int)s1];
            const float w2 = (float)(r2 & 0xFFu) * isq[N + (int)s2];
            const uint4 u1 = *((const uint4*)(HSh + (long)s1 * 32 + c * 4));
            const uint4 u2 = *((const uint4*)(HSh + (long)s2 * 32 + c * 4));
            mi[0] += w1 * bflo(u1.x);  mi[1] += w1 * bfhi(u1.x);
            mi[2] += w1 * bflo(u1.y);  mi[3] += w1 * bfhi(u1.y);
            mi[4] += w1 * bflo(u1.z);  mi[5] += w1 * bfhi(u1.z);
            mi[6] += w1 * bflo(u1.w);  mi[7] += w1 * bfhi(u1.w);
            mi[0] += w2 * bflo(u2.x);  mi[1] += w2 * bfhi(u2.x);
            mi[2] += w2 * bflo(u2.y);  mi[3] += w2 * bfhi(u2.y);
            mi[4] += w2 * bflo(u2.z);  mi[5] += w2 * bfhi(u2.z);
            mi[6] += w2 * bflo(u2.w);  mi[7] += w2 * bfhi(u2.w);
        }
        for (; ii < ei; ii += 8) {                 // tail
            const unsigned r1 = rin[ii];
            const unsigned s1 = r1 >> 16;
            const float w1 = (float)(r1 & 0xFFu) * isq[N + (int)s1];
            const uint4 u1 = *((const uint4*)(HSh + (long)s1 * 32 + c * 4));
            mi[0] += w1 * bflo(u1.x);  mi[1] += w1 * bfhi(u1.x);
            mi[2] += w1 * bflo(u1.y);  mi[3] += w1 * bfhi(u1.y);
            mi[4] += w1 * bflo(u1.z);  mi[5] += w1 * bfhi(u1.z);
            mi[6] += w1 * bflo(u1.w);  mi[7] += w1 * bfhi(u1.w);
        }
        // ---- outbound records (m_out side): w = cnt * isq_in[dst]
        int jo = g;
        for (; jo + 8 < eo; jo += 16) {            // 2-way: jo, jo+8
            const unsigned r1 = rout[jo];
            const unsigned r2 = rout[jo + 8];
            const unsigned s1 = r1 >> 16;
            const unsigned s2 = r2 >> 16;
            const float w1 = (float)(r1 & 0xFFu) * isq[(int)s1];
            const float w2 = (float)(r2 & 0xFFu) * isq[(int)s2];
            const uint4 u1 = *((const uint4*)(HDh + (long)s1 * 32 + c * 4));
            const uint4 u2 = *((const uint4*)(HDh + (long)s2 * 32 + c * 4));
            mo[0] += w1 * bflo(u1.x);  mo[1] += w1 * bfhi(u1.x);
            mo[2] += w1 * bflo(u1.y);  mo[3] += w1 * bfhi(u1.y);
            mo[4] += w1 * bflo(u1.z);  mo[5] += w1 * bfhi(u1.z);
            mo[6] += w1 * bflo(u1.w);  mo[7] += w1 * bfhi(u1.w);
            mo[0] += w2 * bflo(u2.x);  mo[1] += w2 * bfhi(u2.x);
            mo[2] += w2 * bflo(u2.y);  mo[3] += w2 * bfhi(u2.y);
            mo[4] += w2 * bflo(u2.z);  mo[5] += w2 * bfhi(u2.z);
            mo[6] += w2 * bflo(u2.w);  mo[7] += w2 * bfhi(u2.w);
        }
        for (; jo < eo; jo += 8) {                 // tail
            const unsigned r1 = rout[jo];
            const unsigned s1 = r1 >> 16;
            const float w1 = (float)(r1 & 0xFFu) * isq[(int)s1];
            const uint4 u1 = *((const uint4*)(HDh + (long)s1 * 32 + c * 4));
            mo[0] += w1 * bflo(u1.x);  mo[1] += w1 * bfhi(u1.x);
            mo[2] += w1 * bflo(u1.y);  mo[3] += w1 * bfhi(u1.y);
            mo[4] += w1 * bflo(u1.z);  mo[5] += w1 * bfhi(u1.z);
            mo[6] += w1 * bflo(u1.w);  mo[7] += w1 * bfhi(u1.w);
        }

        // reduce the 8 edge groups (lane bits 3,4,5)
#pragma unroll
        for (int q = 0; q < 8; ++q) {
            mi[q] += __shfl_xor(mi[q], 8);
            mi[q] += __shfl_xor(mi[q], 16);
            mi[q] += __shfl_xor(mi[q], 32);
            mo[q] += __shfl_xor(mo[q], 8);
            mo[q] += __shfl_xor(mo[q], 16);
            mo[q] += __shfl_xor(mo[q], 32);
        }
        if (g == 0) {
#pragma unroll
            for (int q = 0; q < 8; ++q) {
                mbuf[row][c * 8 + q]      = mi[q] * qin;    // apply row norm factor
                mbuf[row][64 + c * 8 + q] = mo[q] * qout;
            }
        }
    }
    // wave-local LDS RAW; compiler inserts lgkmcnt wait (no barrier needed)

    const float bgv = bg1[lane];
    float ac0 = bgv, ac1 = bgv, ac2 = bgv, ac3 = bgv;
    const float* m0 = &mbuf[wv * 4 + 0][0];
    const float* m1 = &mbuf[wv * 4 + 1][0];
    const float* m2 = &mbuf[wv * 4 + 2][0];
    const float* m3 = &mbuf[wv * 4 + 3][0];
#pragma unroll 4
    for (int k4 = 0; k4 < 32; ++k4) {
        const float4 w4 = ((const float4*)Wg1q)[k4 * 64 + lane];   // coalesced, L1
        const float4 q0 = ((const float4*)m0)[k4];                 // LDS broadcast
        const float4 q1 = ((const float4*)m1)[k4];
        const float4 q2 = ((const float4*)m2)[k4];
        const float4 q3 = ((const float4*)m3)[k4];
        ac0 += q0.x * w4.x + q0.y * w4.y + q0.z * w4.z + q0.w * w4.w;
        ac1 += q1.x * w4.x + q1.y * w4.y + q1.z * w4.z + q1.w * w4.w;
        ac2 += q2.x * w4.x + q2.y * w4.y + q2.z * w4.z + q2.w * w4.w;
        ac3 += q3.x * w4.x + q3.y * w4.y + q3.z * w4.z + q3.w * w4.w;
    }
    const float wg2 = Wg2[lane];
    float v0 = fmaxf(ac0, 0.f) * wg2;
    float v1 = fmaxf(ac1, 0.f) * wg2;
    float v2 = fmaxf(ac2, 0.f) * wg2;
    float v3 = fmaxf(ac3, 0.f) * wg2;
#pragma unroll
    for (int m = 1; m <= 32; m <<= 1) {
        v0 += __shfl_xor(v0, m);
        v1 += __shfl_xor(v1, m);
        v2 += __shfl_xor(v2, m);
        v3 += __shfl_xor(v3, m);
    }
    const float bb = bg2[0];
    float gt[4];
    gt[0] = 1.f / (1.f + expf(-(v0 + bb)));
    gt[1] = 1.f / (1.f + expf(-(v1 + bb)));
    gt[2] = 1.f / (1.f + expf(-(v2 + bb)));
    gt[3] = 1.f / (1.f + expf(-(v3 + bb)));

#pragma unroll
    for (int j = 0; j < 4; ++j) {
        const int n = nb + j;
        if (n >= N) continue;
        const float miv = mbuf[wv * 4 + j][lane];
        const float mov = mbuf[wv * 4 + j][64 + lane];
        out[(long)n * 64 + lane] = 0.5f * gt[j] * miv + 0.5f * (1.f - gt[j]) * mov
                                 + x[(long)n * 64 + lane];
    }
}

extern "C" void kernel_launch(void* const* d_in, const int* in_sizes, int n_in,
                              void* d_out, int out_size, void* d_ws, size_t ws_size,
                              hipStream_t stream) {
    const float* x      = (const float*)d_in[0];
    const float* counts = (const float*)d_in[1];
    const float* Ws2d   = (const float*)d_in[2];
    const float* bs2d   = (const float*)d_in[3];
    const float* Wd2s   = (const float*)d_in[4];
    const float* bd2s   = (const float*)d_in[5];
    const float* Wl1    = (const float*)d_in[6];
    const float* bl1    = (const float*)d_in[7];
    const float* Wl2    = (const float*)d_in[8];
    const float* bl2    = (const float*)d_in[9];
    const float* Wg1    = (const float*)d_in[10];
    const float* bg1    = (const float*)d_in[11];
    const float* Wg2    = (const float*)d_in[12];
    const float* bg2    = (const float*)d_in[13];
    const int*   src    = (const int*)d_in[14];
    const int*   dst    = (const int*)d_in[15];

    const int N  = in_sizes[0] / 64;
    const int E  = in_sizes[14];
    const int PB = (N + 63) / 64;              // proj blocks

    float* ws      = (float*)d_ws;
    float* Wg1q    = ws;                       // 8192 floats
    float* A       = ws + 8192;                // 64N fp32
    float* B       = A + 64L * N;              // 64N fp32
    unsigned* Ah   = (unsigned*)(B + 64L * N); // 32N packed bf16
    unsigned* Bh   = Ah + 32L * N;
    unsigned* HSh  = Bh + 32L * N;
    unsigned* HDh  = HSh + 32L * N;
    u64* pk        = (u64*)(HDh + 32L * N);    // 2N u64 (even offset -> 8B ok)
    unsigned* rec  = (unsigned*)(pk + 2L * N); // 2N * SLOTS u32 (padded rows)
    float* isq     = (float*)(rec + 2L * N * SLOTS); // 2N floats

    proj_zero_kernel<<<PB + 65, 256, 0, stream>>>(
        x, Wl1, bl1, Ws2d, bs2d, Wd2s, bd2s, Wg1, Wg1q,
        A, B, Ah, Bh, HSh, HDh, (int4*)pk, N, PB, N);   // 2N u64 = N int4

    edge_w_kernel<<<(E + 31) / 32, 256, 0, stream>>>(
        src, dst, counts, A, B, Ah, Bh, Wl2, bl2, pk, rec, N, E);

    isq_kernel<<<(2 * N + 255) / 256, 256, 0, stream>>>(pk, isq, 2 * N);

    gather_gate_kernel<<<(N + 15) / 16, 256, 0, stream>>>(
        pk, rec, isq, HSh, HDh, x, Wg1q, bg1, Wg2, bg2, (float*)d_out, N);
}